// Round 1
// baseline (342.866 us; speedup 1.0000x reference)
//
#include <hip/hip_runtime.h>
#include <hip/hip_cooperative_groups.h>

namespace cg = cooperative_groups;

typedef unsigned short u16;
typedef unsigned int   u32;
typedef __attribute__((ext_vector_type(8))) short short8;   // 8 bf16
typedef __attribute__((ext_vector_type(4))) float f32x4;

__device__ __forceinline__ u16 f2bf(float f) {
    union { float f; u32 i; } v; v.f = f;
    u32 x = v.i;
    return (u16)((x + 0x7fffu + ((x >> 16) & 1u)) >> 16);   // RNE
}
__device__ __forceinline__ float bf2f(u16 u) {
    union { u32 i; float f; } v; v.i = ((u32)u) << 16; return v.f;
}

// ============================================================
// Fused cooperative kernel: conv+transpose | grid.sync | MFMA GEMM
// | grid.sync | MLP tail.  Phase interiors identical to the
// R9-validated k1_fused / k2_mfma / k3_tail.
// 256 blocks x 256 threads, 1 block/CU guaranteed co-resident.
// ============================================================
struct P1 { float img[3][29][96]; float w[216]; float tile[32][33]; }; // 38496 B
struct P2 { u16 sAh[64 * 40]; u16 sAl[64 * 40]; u16 sBh[64 * 40]; u16 sBl[64 * 40]; }; // 20480 B
union SMem { P1 p1; P2 p2; };

__global__ __launch_bounds__(256) void k_all(
    const float* __restrict__ images,   // (1024,3,96,96)
    const float* __restrict__ conv_w,   // (8,3,3,3)
    const float* __restrict__ ft_w,     // (800,1024)
    const float* __restrict__ ft_b,     // (1024,)
    const float* __restrict__ w1, const float* __restrict__ b1,
    const float* __restrict__ w2, const float* __restrict__ b2,
    const float* __restrict__ w3, const float* __restrict__ b3,
    float* __restrict__ out,            // (1024,)
    u16* __restrict__ vh, u16* __restrict__ vl,     // (1024,800)
    u16* __restrict__ bth, u16* __restrict__ btl,   // (1024,800) n-major
    float* __restrict__ l0)             // (1024,1024)
{
    __shared__ SMem smem;
    int t = threadIdx.x;

    // ---------------- Phase 1: conv + ft_w transpose/split ----------------
    for (int job = blockIdx.x; job < 1824; job += 256) {
        __syncthreads();                      // LDS reuse across jobs
        if (job >= 1024) {
            int bid = job - 1024;             // 0..799
            int kb = bid / 32, nb = bid - kb * 32;
            int k0 = kb * 32, n0 = nb * 32;
            int tx = t & 31, ty = t >> 5;     // ty 0..7
            #pragma unroll
            for (int i = 0; i < 4; i++) {
                int k = ty + i * 8;
                smem.p1.tile[k][tx] = ft_w[(k0 + k) * 1024 + n0 + tx];
            }
            __syncthreads();
            #pragma unroll
            for (int i = 0; i < 4; i++) {
                int n = ty + i * 8;
                float wv = smem.p1.tile[tx][n];
                u16 hi = f2bf(wv);
                float lo = wv - bf2f(hi);
                bth[(n0 + n) * 800 + k0 + tx] = hi;
                btl[(n0 + n) * 800 + k0 + tx] = f2bf(lo);
            }
        } else {
            int b = job;
            if (t < 216) smem.p1.w[t] = conv_w[t];
            for (int i = t; i < 3 * 29 * 96; i += 256) {
                int ch  = i / (29 * 96);
                int rem = i - ch * (29 * 96);
                int lr  = rem / 96;
                int x   = rem - lr * 96;
                int ih  = 10 * ((lr + 1) / 3) + (lr + 1) % 3 - 1;
                smem.p1.img[ch][lr][x] = images[((b * 3 + ch) * 96 + ih) * 96 + x];
            }
            __syncthreads();

            for (int ridx = t; ridx < 800; ridx += 256) {
                int o  = ridx / 100;
                int p  = ridx - o * 100;
                int oh = p / 10;
                int ow = p - oh * 10;

                float sum = 0.0f;
                #pragma unroll
                for (int ic = 0; ic < 3; ic++) {
                    const float* wc = &smem.p1.w[o * 27 + ic * 9];
                    #pragma unroll
                    for (int kh = 0; kh < 3; kh++) {
                        int lr = 3 * oh + kh - 1;
                        if (lr < 0) continue;
                        #pragma unroll
                        for (int kw = 0; kw < 3; kw++) {
                            int iw = ow * 10 + kw - 1;
                            if (iw < 0) continue;
                            sum = fmaf(smem.p1.img[ic][lr][iw], wc[kh * 3 + kw], sum);
                        }
                    }
                }
                float xc = fminf(fmaxf(sum, -1.0f), 1.0f);
                float binary = 1.0f / (1.0f + __expf(-10.0f * xc));
                float v = (binary > 0.5f) ? binary : 0.0f;
                u16 hi = f2bf(v);
                vh[b * 800 + ridx] = hi;
                vl[b * 800 + ridx] = f2bf(v - bf2f(hi));
            }
        }
    }

    cg::this_grid().sync();

    // ---------------- Phase 2: split-bf16 MFMA GEMM (64x64 tile) ----------------
    {
        u16* sAh = smem.p2.sAh; u16* sAl = smem.p2.sAl;
        u16* sBh = smem.p2.sBh; u16* sBl = smem.p2.sBl;

        int m0 = (blockIdx.x >> 4) * 64, n0 = (blockIdx.x & 15) * 64;
        int w = t >> 6, lane = t & 63;
        int quad = lane >> 4, lo4 = lane & 15;
        int wm = (w >> 1) * 32, wn = (w & 1) * 32;

        int sr = t >> 2;   // staging row 0..63
        int sq = t & 3;    // 8-elem chunk 0..3
        const u16* gAh = vh + (m0 + sr) * 800 + sq * 8;
        const u16* gAl = vl + (m0 + sr) * 800 + sq * 8;
        const u16* gBh = bth + (n0 + sr) * 800 + sq * 8;
        const u16* gBl = btl + (n0 + sr) * 800 + sq * 8;
        int sdst = sr * 40 + sq * 8;

        f32x4 acc[2][2] = {};

        uint4 rAh = *(const uint4*)(gAh);
        uint4 rAl = *(const uint4*)(gAl);
        uint4 rBh = *(const uint4*)(gBh);
        uint4 rBl = *(const uint4*)(gBl);

        for (int k0 = 0; k0 < 800; k0 += 32) {
            *(uint4*)&sAh[sdst] = rAh;
            *(uint4*)&sAl[sdst] = rAl;
            *(uint4*)&sBh[sdst] = rBh;
            *(uint4*)&sBl[sdst] = rBl;
            __syncthreads();

            if (k0 + 32 < 800) {               // prefetch next tile
                rAh = *(const uint4*)(gAh + k0 + 32);
                rAl = *(const uint4*)(gAl + k0 + 32);
                rBh = *(const uint4*)(gBh + k0 + 32);
                rBl = *(const uint4*)(gBl + k0 + 32);
            }

            short8 a_h[2], a_l[2], b_h[2], b_l[2];
            #pragma unroll
            for (int f = 0; f < 2; f++) {
                int mi = (wm + f * 16 + lo4) * 40 + quad * 8;
                a_h[f] = *(const short8*)&sAh[mi];
                a_l[f] = *(const short8*)&sAl[mi];
                int ni = (wn + f * 16 + lo4) * 40 + quad * 8;
                b_h[f] = *(const short8*)&sBh[ni];
                b_l[f] = *(const short8*)&sBl[ni];
            }
            #pragma unroll
            for (int fm = 0; fm < 2; fm++)
                #pragma unroll
                for (int fn = 0; fn < 2; fn++) {
                    acc[fm][fn] = __builtin_amdgcn_mfma_f32_16x16x32_bf16(a_h[fm], b_h[fn], acc[fm][fn], 0, 0, 0);
                    acc[fm][fn] = __builtin_amdgcn_mfma_f32_16x16x32_bf16(a_h[fm], b_l[fn], acc[fm][fn], 0, 0, 0);
                    acc[fm][fn] = __builtin_amdgcn_mfma_f32_16x16x32_bf16(a_l[fm], b_h[fn], acc[fm][fn], 0, 0, 0);
                }
            __syncthreads();
        }

        // C/D layout: col = lane&15, row = quad*4 + reg
        #pragma unroll
        for (int fm = 0; fm < 2; fm++) {
            #pragma unroll
            for (int fn = 0; fn < 2; fn++) {
                int n = n0 + wn + fn * 16 + lo4;
                float bv = ft_b[n];
                #pragma unroll
                for (int r = 0; r < 4; r++) {
                    int m = m0 + wm + fm * 16 + quad * 4 + r;
                    float v = acc[fm][fn][r] + bv;
                    l0[m * 1024 + n] = fminf(fmaxf(v, 0.f), 1.f);
                }
            }
        }
    }

    cg::this_grid().sync();

    // ---------------- Phase 3: per-row MLP tail (1 row per wave) ----------------
    {
        int wave = t >> 6;
        int lane = t & 63;
        int b = blockIdx.x * 4 + wave;
        const float* row = l0 + b * 1024;
        const float cc = 0.9921875f;   // 127/128

        float acc[15];
        #pragma unroll
        for (int j = 0; j < 15; j++) acc[j] = 0.f;

        #pragma unroll
        for (int i = 0; i < 2; i++) {
            int k4 = (lane + i * 64) * 4;            // 0..508 step 4
            float4 x0 = *(const float4*)(row + k4);
            float4 x1 = *(const float4*)(row + k4 + 512);
            float4 va, vb;
            va.x = x0.x * x1.x * cc; va.y = x0.y * x1.y * cc;
            va.z = x0.z * x1.z * cc; va.w = x0.w * x1.w * cc;
            vb.x = x0.x * cc; vb.y = x0.y * cc;
            vb.z = x0.z * cc; vb.w = x0.w * cc;
            #pragma unroll
            for (int j = 0; j < 15; j++) {
                float4 wa = *(const float4*)(w1 + j * 1024 + k4);
                float4 wb = *(const float4*)(w1 + j * 1024 + k4 + 512);
                acc[j] = fmaf(va.x, wa.x, acc[j]); acc[j] = fmaf(va.y, wa.y, acc[j]);
                acc[j] = fmaf(va.z, wa.z, acc[j]); acc[j] = fmaf(va.w, wa.w, acc[j]);
                acc[j] = fmaf(vb.x, wb.x, acc[j]); acc[j] = fmaf(vb.y, wb.y, acc[j]);
                acc[j] = fmaf(vb.z, wb.z, acc[j]); acc[j] = fmaf(vb.w, wb.w, acc[j]);
            }
        }

        #pragma unroll
        for (int j = 0; j < 15; j++) {
            #pragma unroll
            for (int m = 32; m >= 1; m >>= 1)
                acc[j] += __shfl_xor(acc[j], m, 64);
        }
        float h1[15];
        #pragma unroll
        for (int j = 0; j < 15; j++) h1[j] = fmaxf(acc[j] + b1[j], 0.f);

        float contrib = 0.f;
        if (lane < 32) {
            float h2 = b2[lane];
            #pragma unroll
            for (int j = 0; j < 15; j++) h2 = fmaf(h1[j], w2[lane * 15 + j], h2);
            h2 = fmaxf(h2, 0.f);
            contrib = h2 * w3[lane];
        }
        #pragma unroll
        for (int m = 32; m >= 1; m >>= 1) contrib += __shfl_xor(contrib, m, 64);

        if (lane == 0) out[b] = contrib + b3[0];
    }
}

// ============================================================
// Fallback path: the original validated 3-kernel pipeline, used
// only if cooperative launch is unavailable at runtime.
// ============================================================
__global__ __launch_bounds__(256) void k1_fused(
    const float* __restrict__ images,
    const float* __restrict__ conv_w,
    const float* __restrict__ ft_w,
    u16* __restrict__ vh, u16* __restrict__ vl,
    u16* __restrict__ bth, u16* __restrict__ btl)
{
    __shared__ float img_s[3][29][96];
    __shared__ float w[216];
    __shared__ float tile[32][33];

    int t = threadIdx.x;

    if (blockIdx.x >= 1024) {
        int bid = blockIdx.x - 1024;
        int kb = bid / 32, nb = bid - kb * 32;
        int k0 = kb * 32, n0 = nb * 32;
        int tx = t & 31, ty = t >> 5;
        #pragma unroll
        for (int i = 0; i < 4; i++) {
            int k = ty + i * 8;
            tile[k][tx] = ft_w[(k0 + k) * 1024 + n0 + tx];
        }
        __syncthreads();
        #pragma unroll
        for (int i = 0; i < 4; i++) {
            int n = ty + i * 8;
            float wv = tile[tx][n];
            u16 hi = f2bf(wv);
            float lo = wv - bf2f(hi);
            bth[(n0 + n) * 800 + k0 + tx] = hi;
            btl[(n0 + n) * 800 + k0 + tx] = f2bf(lo);
        }
        return;
    }

    int b = blockIdx.x;
    if (t < 216) w[t] = conv_w[t];

    for (int i = t; i < 3 * 29 * 96; i += 256) {
        int ch  = i / (29 * 96);
        int rem = i - ch * (29 * 96);
        int lr  = rem / 96;
        int x   = rem - lr * 96;
        int ih  = 10 * ((lr + 1) / 3) + (lr + 1) % 3 - 1;
        img_s[ch][lr][x] = images[((b * 3 + ch) * 96 + ih) * 96 + x];
    }
    __syncthreads();

    for (int ridx = t; ridx < 800; ridx += 256) {
        int o  = ridx / 100;
        int p  = ridx - o * 100;
        int oh = p / 10;
        int ow = p - oh * 10;

        float sum = 0.0f;
        #pragma unroll
        for (int ic = 0; ic < 3; ic++) {
            const float* wc = &w[o * 27 + ic * 9];
            #pragma unroll
            for (int kh = 0; kh < 3; kh++) {
                int lr = 3 * oh + kh - 1;
                if (lr < 0) continue;
                #pragma unroll
                for (int kw = 0; kw < 3; kw++) {
                    int iw = ow * 10 + kw - 1;
                    if (iw < 0) continue;
                    sum = fmaf(img_s[ic][lr][iw], wc[kh * 3 + kw], sum);
                }
            }
        }
        float xc = fminf(fmaxf(sum, -1.0f), 1.0f);
        float binary = 1.0f / (1.0f + __expf(-10.0f * xc));
        float v = (binary > 0.5f) ? binary : 0.0f;
        u16 hi = f2bf(v);
        vh[b * 800 + ridx] = hi;
        vl[b * 800 + ridx] = f2bf(v - bf2f(hi));
    }
}

__global__ __launch_bounds__(256) void k2_mfma(
    const u16* __restrict__ Ah, const u16* __restrict__ Al,
    const u16* __restrict__ Bh, const u16* __restrict__ Bl,
    const float* __restrict__ bias,
    float* __restrict__ C)
{
    __shared__ u16 sAh[64 * 40], sAl[64 * 40], sBh[64 * 40], sBl[64 * 40];
    int t = threadIdx.x;
    int m0 = blockIdx.y * 64, n0 = blockIdx.x * 64;
    int w = t >> 6, lane = t & 63;
    int quad = lane >> 4, lo4 = lane & 15;
    int wm = (w >> 1) * 32, wn = (w & 1) * 32;

    int sr = t >> 2;
    int sq = t & 3;
    const u16* gAh = Ah + (m0 + sr) * 800 + sq * 8;
    const u16* gAl = Al + (m0 + sr) * 800 + sq * 8;
    const u16* gBh = Bh + (n0 + sr) * 800 + sq * 8;
    const u16* gBl = Bl + (n0 + sr) * 800 + sq * 8;
    int sdst = sr * 40 + sq * 8;

    f32x4 acc[2][2] = {};

    uint4 rAh = *(const uint4*)(gAh);
    uint4 rAl = *(const uint4*)(gAl);
    uint4 rBh = *(const uint4*)(gBh);
    uint4 rBl = *(const uint4*)(gBl);

    for (int k0 = 0; k0 < 800; k0 += 32) {
        *(uint4*)&sAh[sdst] = rAh;
        *(uint4*)&sAl[sdst] = rAl;
        *(uint4*)&sBh[sdst] = rBh;
        *(uint4*)&sBl[sdst] = rBl;
        __syncthreads();

        if (k0 + 32 < 800) {
            rAh = *(const uint4*)(gAh + k0 + 32);
            rAl = *(const uint4*)(gAl + k0 + 32);
            rBh = *(const uint4*)(gBh + k0 + 32);
            rBl = *(const uint4*)(gBl + k0 + 32);
        }

        short8 a_h[2], a_l[2], b_h[2], b_l[2];
        #pragma unroll
        for (int f = 0; f < 2; f++) {
            int mi = (wm + f * 16 + lo4) * 40 + quad * 8;
            a_h[f] = *(const short8*)&sAh[mi];
            a_l[f] = *(const short8*)&sAl[mi];
            int ni = (wn + f * 16 + lo4) * 40 + quad * 8;
            b_h[f] = *(const short8*)&sBh[ni];
            b_l[f] = *(const short8*)&sBl[ni];
        }
        #pragma unroll
        for (int fm = 0; fm < 2; fm++)
            #pragma unroll
            for (int fn = 0; fn < 2; fn++) {
                acc[fm][fn] = __builtin_amdgcn_mfma_f32_16x16x32_bf16(a_h[fm], b_h[fn], acc[fm][fn], 0, 0, 0);
                acc[fm][fn] = __builtin_amdgcn_mfma_f32_16x16x32_bf16(a_h[fm], b_l[fn], acc[fm][fn], 0, 0, 0);
                acc[fm][fn] = __builtin_amdgcn_mfma_f32_16x16x32_bf16(a_l[fm], b_h[fn], acc[fm][fn], 0, 0, 0);
            }
        __syncthreads();
    }

    #pragma unroll
    for (int fm = 0; fm < 2; fm++) {
        #pragma unroll
        for (int fn = 0; fn < 2; fn++) {
            int n = n0 + wn + fn * 16 + lo4;
            float bv = bias[n];
            #pragma unroll
            for (int r = 0; r < 4; r++) {
                int m = m0 + wm + fm * 16 + quad * 4 + r;
                float v = acc[fm][fn][r] + bv;
                C[m * 1024 + n] = fminf(fmaxf(v, 0.f), 1.f);
            }
        }
    }
}

__global__ __launch_bounds__(256) void k3_tail(
    const float* __restrict__ l0,
    const float* __restrict__ w1,
    const float* __restrict__ b1,
    const float* __restrict__ w2,
    const float* __restrict__ b2,
    const float* __restrict__ w3,
    const float* __restrict__ b3,
    float* __restrict__ out)
{
    int wave = threadIdx.x >> 6;
    int lane = threadIdx.x & 63;
    int b = blockIdx.x * 4 + wave;
    const float* row = l0 + b * 1024;
    const float cc = 0.9921875f;

    float acc[15];
    #pragma unroll
    for (int j = 0; j < 15; j++) acc[j] = 0.f;

    #pragma unroll
    for (int i = 0; i < 2; i++) {
        int k4 = (lane + i * 64) * 4;
        float4 x0 = *(const float4*)(row + k4);
        float4 x1 = *(const float4*)(row + k4 + 512);
        float4 va, vb;
        va.x = x0.x * x1.x * cc; va.y = x0.y * x1.y * cc;
        va.z = x0.z * x1.z * cc; va.w = x0.w * x1.w * cc;
        vb.x = x0.x * cc; vb.y = x0.y * cc;
        vb.z = x0.z * cc; vb.w = x0.w * cc;
        #pragma unroll
        for (int j = 0; j < 15; j++) {
            float4 wa = *(const float4*)(w1 + j * 1024 + k4);
            float4 wb = *(const float4*)(w1 + j * 1024 + k4 + 512);
            acc[j] = fmaf(va.x, wa.x, acc[j]); acc[j] = fmaf(va.y, wa.y, acc[j]);
            acc[j] = fmaf(va.z, wa.z, acc[j]); acc[j] = fmaf(va.w, wa.w, acc[j]);
            acc[j] = fmaf(vb.x, wb.x, acc[j]); acc[j] = fmaf(vb.y, wb.y, acc[j]);
            acc[j] = fmaf(vb.z, wb.z, acc[j]); acc[j] = fmaf(vb.w, wb.w, acc[j]);
        }
    }

    #pragma unroll
    for (int j = 0; j < 15; j++) {
        #pragma unroll
        for (int m = 32; m >= 1; m >>= 1)
            acc[j] += __shfl_xor(acc[j], m, 64);
    }
    float h1[15];
    #pragma unroll
    for (int j = 0; j < 15; j++) h1[j] = fmaxf(acc[j] + b1[j], 0.f);

    float contrib = 0.f;
    if (lane < 32) {
        float h2 = b2[lane];
        #pragma unroll
        for (int j = 0; j < 15; j++) h2 = fmaf(h1[j], w2[lane * 15 + j], h2);
        h2 = fmaxf(h2, 0.f);
        contrib = h2 * w3[lane];
    }
    #pragma unroll
    for (int m = 32; m >= 1; m >>= 1) contrib += __shfl_xor(contrib, m, 64);

    if (lane == 0) out[b] = contrib + b3[0];
}

// ============================================================
extern "C" void kernel_launch(void* const* d_in, const int* in_sizes, int n_in,
                              void* d_out, int out_size, void* d_ws, size_t ws_size,
                              hipStream_t stream) {
    const float* images = (const float*)d_in[0];
    const float* conv_w = (const float*)d_in[1];
    const float* ft_w   = (const float*)d_in[2];
    const float* ft_b   = (const float*)d_in[3];
    const float* w1     = (const float*)d_in[4];
    const float* b1     = (const float*)d_in[5];
    const float* w2     = (const float*)d_in[6];
    const float* b2     = (const float*)d_in[7];
    const float* w3     = (const float*)d_in[8];
    const float* b3     = (const float*)d_in[9];
    float* out = (float*)d_out;

    const int NV = 1024 * 800;                 // 819200
    u16* vh  = (u16*)d_ws;
    u16* vl  = vh + NV;
    u16* bth = vl + NV;
    u16* btl = bth + NV;
    float* l0 = (float*)(btl + NV);            // (1024,1024) f32

    void* kargs[] = {
        (void*)&images, (void*)&conv_w, (void*)&ft_w, (void*)&ft_b,
        (void*)&w1, (void*)&b1, (void*)&w2, (void*)&b2, (void*)&w3, (void*)&b3,
        (void*)&out, (void*)&vh, (void*)&vl, (void*)&bth, (void*)&btl, (void*)&l0
    };
    hipError_t e = hipLaunchCooperativeKernel(k_all, dim3(256), dim3(256),
                                              kargs, 0, stream);
    if (e != hipSuccess) {
        // Fallback: validated 3-kernel pipeline
        k1_fused<<<1824, 256, 0, stream>>>(images, conv_w, ft_w, vh, vl, bth, btl);
        k2_mfma<<<dim3(16, 16), 256, 0, stream>>>(vh, vl, bth, btl, ft_b, l0);
        k3_tail<<<256, 256, 0, stream>>>(l0, w1, b1, w2, b2, w3, b3, out);
    }
}

// Round 2
// 207.821 us; speedup vs baseline: 1.6498x; 1.6498x over previous
//
#include <hip/hip_runtime.h>

typedef unsigned short u16;
typedef unsigned int   u32;
typedef __attribute__((ext_vector_type(8))) short short8;   // 8 bf16
typedef __attribute__((ext_vector_type(4))) float f32x4;

__device__ __forceinline__ u16 f2bf(float f) {
    union { float f; u32 i; } v; v.f = f;
    u32 x = v.i;
    return (u16)((x + 0x7fffu + ((x >> 16) & 1u)) >> 16);   // RNE
}
__device__ __forceinline__ float bf2f(u16 u) {
    union { u32 i; float f; } v; v.i = ((u32)u) << 16; return v.f;
}

// ============================================================
// K1 (fused, full-parallel) [R9-validated; this round: img_s inner
// dim padded 96->100 so Δoh LDS stride = 300 floats ≡ 12 mod 32
// banks (was 288 ≡ 0 → ~6-way conflict, 3.6M conflict cycles seen
// in the round-1 fused profile).]
// blocks [0,1024): conv; blocks [1024,1824): one 32x32 ft_w
// transpose+split tile per block.
// ============================================================
__global__ __launch_bounds__(256) void k1_fused(
    const float* __restrict__ images,   // (1024,3,96,96)
    const float* __restrict__ conv_w,   // (8,3,3,3)
    const float* __restrict__ ft_w,     // (800,1024)
    u16* __restrict__ vh, u16* __restrict__ vl,     // (1024,800)
    u16* __restrict__ bth, u16* __restrict__ btl)   // (1024,800) n-major
{
    __shared__ float img_s[3][29][100];   // padded (was 96)
    __shared__ float w[216];
    __shared__ float tile[32][33];

    int t = threadIdx.x;

    if (blockIdx.x >= 1024) {
        int bid = blockIdx.x - 1024;       // 0..799
        int kb = bid / 32, nb = bid - kb * 32;
        int k0 = kb * 32, n0 = nb * 32;
        int tx = t & 31, ty = t >> 5;      // ty 0..7
        #pragma unroll
        for (int i = 0; i < 4; i++) {
            int k = ty + i * 8;
            tile[k][tx] = ft_w[(k0 + k) * 1024 + n0 + tx];
        }
        __syncthreads();
        #pragma unroll
        for (int i = 0; i < 4; i++) {
            int n = ty + i * 8;
            float wv = tile[tx][n];
            u16 hi = f2bf(wv);
            float lo = wv - bf2f(hi);
            bth[(n0 + n) * 800 + k0 + tx] = hi;
            btl[(n0 + n) * 800 + k0 + tx] = f2bf(lo);
        }
        return;
    }

    int b = blockIdx.x;
    if (t < 216) w[t] = conv_w[t];

    for (int i = t; i < 3 * 29 * 96; i += 256) {
        int ch  = i / (29 * 96);
        int rem = i - ch * (29 * 96);
        int lr  = rem / 96;
        int x   = rem - lr * 96;
        int ih  = 10 * ((lr + 1) / 3) + (lr + 1) % 3 - 1;
        img_s[ch][lr][x] = images[((b * 3 + ch) * 96 + ih) * 96 + x];
    }
    __syncthreads();

    for (int ridx = t; ridx < 800; ridx += 256) {
        int o  = ridx / 100;
        int p  = ridx - o * 100;
        int oh = p / 10;
        int ow = p - oh * 10;

        float sum = 0.0f;
        #pragma unroll
        for (int ic = 0; ic < 3; ic++) {
            const float* wc = &w[o * 27 + ic * 9];
            #pragma unroll
            for (int kh = 0; kh < 3; kh++) {
                int lr = 3 * oh + kh - 1;
                if (lr < 0) continue;
                #pragma unroll
                for (int kw = 0; kw < 3; kw++) {
                    int iw = ow * 10 + kw - 1;
                    if (iw < 0) continue;
                    sum = fmaf(img_s[ic][lr][iw], wc[kh * 3 + kw], sum);
                }
            }
        }
        float xc = fminf(fmaxf(sum, -1.0f), 1.0f);
        float binary = 1.0f / (1.0f + __expf(-10.0f * xc));
        float v = (binary > 0.5f) ? binary : 0.0f;
        u16 hi = f2bf(v);
        vh[b * 800 + ridx] = hi;
        vl[b * 800 + ridx] = f2bf(v - bf2f(hi));
    }
}

// ============================================================
// K2: split-bf16 MFMA GEMM, 64x64 tile, 4 waves, 2x2 frags,
// register-prefetch pipelining. THIS ROUND: split-K x2 via
// blockIdx.z (k in [0,416) / [416,800)) -> 512 blocks = 2
// blocks/CU = 8 waves/CU (was 1 block/CU, 1 wave/SIMD,
// latency-starved). Partials written RAW (no bias/clip) to two
// f32 buffers; K3 reduces.
// ============================================================
__global__ __launch_bounds__(256) void k2_mfma(
    const u16* __restrict__ Ah, const u16* __restrict__ Al,   // (1024,800)
    const u16* __restrict__ Bh, const u16* __restrict__ Bl,   // (1024,800) n-major
    float* __restrict__ C0, float* __restrict__ C1)           // (1024,1024) partials
{
    __shared__ u16 sAh[64 * 40], sAl[64 * 40], sBh[64 * 40], sBl[64 * 40];
    int t = threadIdx.x;
    int m0 = blockIdx.y * 64, n0 = blockIdx.x * 64;
    int kb = (blockIdx.z == 0) ? 0 : 416;
    int ke = (blockIdx.z == 0) ? 416 : 800;
    float* C = (blockIdx.z == 0) ? C0 : C1;

    int w = t >> 6, lane = t & 63;
    int quad = lane >> 4, lo4 = lane & 15;
    int wm = (w >> 1) * 32, wn = (w & 1) * 32;

    int sr = t >> 2;   // staging row 0..63
    int sq = t & 3;    // 8-elem chunk 0..3
    const u16* gAh = Ah + (m0 + sr) * 800 + sq * 8;
    const u16* gAl = Al + (m0 + sr) * 800 + sq * 8;
    const u16* gBh = Bh + (n0 + sr) * 800 + sq * 8;
    const u16* gBl = Bl + (n0 + sr) * 800 + sq * 8;
    int sdst = sr * 40 + sq * 8;

    f32x4 acc[2][2] = {};

    uint4 rAh = *(const uint4*)(gAh + kb);
    uint4 rAl = *(const uint4*)(gAl + kb);
    uint4 rBh = *(const uint4*)(gBh + kb);
    uint4 rBl = *(const uint4*)(gBl + kb);

    for (int k0 = kb; k0 < ke; k0 += 32) {
        *(uint4*)&sAh[sdst] = rAh;
        *(uint4*)&sAl[sdst] = rAl;
        *(uint4*)&sBh[sdst] = rBh;
        *(uint4*)&sBl[sdst] = rBl;
        __syncthreads();

        if (k0 + 32 < ke) {                // prefetch next tile
            rAh = *(const uint4*)(gAh + k0 + 32);
            rAl = *(const uint4*)(gAl + k0 + 32);
            rBh = *(const uint4*)(gBh + k0 + 32);
            rBl = *(const uint4*)(gBl + k0 + 32);
        }

        short8 a_h[2], a_l[2], b_h[2], b_l[2];
        #pragma unroll
        for (int f = 0; f < 2; f++) {
            int mi = (wm + f * 16 + lo4) * 40 + quad * 8;
            a_h[f] = *(const short8*)&sAh[mi];
            a_l[f] = *(const short8*)&sAl[mi];
            int ni = (wn + f * 16 + lo4) * 40 + quad * 8;
            b_h[f] = *(const short8*)&sBh[ni];
            b_l[f] = *(const short8*)&sBl[ni];
        }
        #pragma unroll
        for (int fm = 0; fm < 2; fm++)
            #pragma unroll
            for (int fn = 0; fn < 2; fn++) {
                acc[fm][fn] = __builtin_amdgcn_mfma_f32_16x16x32_bf16(a_h[fm], b_h[fn], acc[fm][fn], 0, 0, 0);
                acc[fm][fn] = __builtin_amdgcn_mfma_f32_16x16x32_bf16(a_h[fm], b_l[fn], acc[fm][fn], 0, 0, 0);
                acc[fm][fn] = __builtin_amdgcn_mfma_f32_16x16x32_bf16(a_l[fm], b_h[fn], acc[fm][fn], 0, 0, 0);
            }
        __syncthreads();
    }

    // C/D layout: col = lane&15, row = quad*4 + reg.  Raw partial store.
    #pragma unroll
    for (int fm = 0; fm < 2; fm++) {
        #pragma unroll
        for (int fn = 0; fn < 2; fn++) {
            int n = n0 + wn + fn * 16 + lo4;
            #pragma unroll
            for (int r = 0; r < 4; r++) {
                int m = m0 + wm + fm * 16 + quad * 4 + r;
                C[m * 1024 + n] = acc[fm][fn][r];
            }
        }
    }
}

// ============================================================
// K3: per-row tail, one wave per row, 4 waves/block, float4 loads.
// THIS ROUND: reduces the two split-K partials + ft_b + clip
// inline (bias/clip moved here from K2).
// ============================================================
__global__ __launch_bounds__(256) void k3_tail(
    const float* __restrict__ l0a, // (1024,1024) partial 0
    const float* __restrict__ l0b, // (1024,1024) partial 1
    const float* __restrict__ ft_b,// (1024,)
    const float* __restrict__ w1,  // (15,1024)
    const float* __restrict__ b1,
    const float* __restrict__ w2,  // (32,15)
    const float* __restrict__ b2,
    const float* __restrict__ w3,  // (1,32)
    const float* __restrict__ b3,
    float* __restrict__ out)       // (1024,)
{
    int wave = threadIdx.x >> 6;
    int lane = threadIdx.x & 63;
    int b = blockIdx.x * 4 + wave;
    const float* pa = l0a + b * 1024;
    const float* pb = l0b + b * 1024;
    const float cc = 0.9921875f;   // 127/128

    float acc[15];
    #pragma unroll
    for (int j = 0; j < 15; j++) acc[j] = 0.f;

    #pragma unroll
    for (int i = 0; i < 2; i++) {
        int k4 = (lane + i * 64) * 4;            // 0..508 step 4
        float4 a0 = *(const float4*)(pa + k4);
        float4 q0 = *(const float4*)(pb + k4);
        float4 f0 = *(const float4*)(ft_b + k4);
        float4 a1 = *(const float4*)(pa + k4 + 512);
        float4 q1 = *(const float4*)(pb + k4 + 512);
        float4 f1 = *(const float4*)(ft_b + k4 + 512);
        float4 x0, x1;
        x0.x = fminf(fmaxf(a0.x + q0.x + f0.x, 0.f), 1.f);
        x0.y = fminf(fmaxf(a0.y + q0.y + f0.y, 0.f), 1.f);
        x0.z = fminf(fmaxf(a0.z + q0.z + f0.z, 0.f), 1.f);
        x0.w = fminf(fmaxf(a0.w + q0.w + f0.w, 0.f), 1.f);
        x1.x = fminf(fmaxf(a1.x + q1.x + f1.x, 0.f), 1.f);
        x1.y = fminf(fmaxf(a1.y + q1.y + f1.y, 0.f), 1.f);
        x1.z = fminf(fmaxf(a1.z + q1.z + f1.z, 0.f), 1.f);
        x1.w = fminf(fmaxf(a1.w + q1.w + f1.w, 0.f), 1.f);

        float4 va, vb;
        va.x = x0.x * x1.x * cc; va.y = x0.y * x1.y * cc;
        va.z = x0.z * x1.z * cc; va.w = x0.w * x1.w * cc;
        vb.x = x0.x * cc; vb.y = x0.y * cc;
        vb.z = x0.z * cc; vb.w = x0.w * cc;
        #pragma unroll
        for (int j = 0; j < 15; j++) {
            float4 wa = *(const float4*)(w1 + j * 1024 + k4);
            float4 wb = *(const float4*)(w1 + j * 1024 + k4 + 512);
            acc[j] = fmaf(va.x, wa.x, acc[j]); acc[j] = fmaf(va.y, wa.y, acc[j]);
            acc[j] = fmaf(va.z, wa.z, acc[j]); acc[j] = fmaf(va.w, wa.w, acc[j]);
            acc[j] = fmaf(vb.x, wb.x, acc[j]); acc[j] = fmaf(vb.y, wb.y, acc[j]);
            acc[j] = fmaf(vb.z, wb.z, acc[j]); acc[j] = fmaf(vb.w, wb.w, acc[j]);
        }
    }

    #pragma unroll
    for (int j = 0; j < 15; j++) {
        #pragma unroll
        for (int m = 32; m >= 1; m >>= 1)
            acc[j] += __shfl_xor(acc[j], m, 64);
    }
    float h1[15];
    #pragma unroll
    for (int j = 0; j < 15; j++) h1[j] = fmaxf(acc[j] + b1[j], 0.f);

    float contrib = 0.f;
    if (lane < 32) {
        float h2 = b2[lane];
        #pragma unroll
        for (int j = 0; j < 15; j++) h2 = fmaf(h1[j], w2[lane * 15 + j], h2);
        h2 = fmaxf(h2, 0.f);
        contrib = h2 * w3[lane];
    }
    #pragma unroll
    for (int m = 32; m >= 1; m >>= 1) contrib += __shfl_xor(contrib, m, 64);

    if (lane == 0) out[b] = contrib + b3[0];
}

// ============================================================
extern "C" void kernel_launch(void* const* d_in, const int* in_sizes, int n_in,
                              void* d_out, int out_size, void* d_ws, size_t ws_size,
                              hipStream_t stream) {
    const float* images = (const float*)d_in[0];
    const float* conv_w = (const float*)d_in[1];
    const float* ft_w   = (const float*)d_in[2];
    const float* ft_b   = (const float*)d_in[3];
    const float* w1     = (const float*)d_in[4];
    const float* b1     = (const float*)d_in[5];
    const float* w2     = (const float*)d_in[6];
    const float* b2     = (const float*)d_in[7];
    const float* w3     = (const float*)d_in[8];
    const float* b3     = (const float*)d_in[9];
    float* out = (float*)d_out;

    const int NV = 1024 * 800;                 // 819200
    u16* vh  = (u16*)d_ws;
    u16* vl  = vh + NV;
    u16* bth = vl + NV;
    u16* btl = bth + NV;
    float* l0a = (float*)(btl + NV);           // (1024,1024) f32 partial 0
    float* l0b = l0a + 1024 * 1024;            // (1024,1024) f32 partial 1

    k1_fused<<<1824, 256, 0, stream>>>(images, conv_w, ft_w, vh, vl, bth, btl);
    k2_mfma<<<dim3(16, 16, 2), 256, 0, stream>>>(vh, vl, bth, btl, l0a, l0b);
    k3_tail<<<256, 256, 0, stream>>>(l0a, l0b, ft_b, w1, b1, w2, b2, w3, b3, out);
}

// Round 3
// 190.636 us; speedup vs baseline: 1.7985x; 1.0901x over previous
//
#include <hip/hip_runtime.h>

typedef unsigned short u16;
typedef unsigned int   u32;
typedef __attribute__((ext_vector_type(8))) short short8;   // 8 bf16
typedef __attribute__((ext_vector_type(4))) float f32x4;

__device__ __forceinline__ u16 f2bf(float f) {
    union { float f; u32 i; } v; v.f = f;
    u32 x = v.i;
    return (u16)((x + 0x7fffu + ((x >> 16) & 1u)) >> 16);   // RNE
}
__device__ __forceinline__ float bf2f(u16 u) {
    union { u32 i; float f; } v; v.i = ((u32)u) << 16; return v.f;
}

// ============================================================
// K1 (fused, full-parallel).  This round: image staging loads
// vectorized to float4 (2088 x 16B instead of 8352 scalar dwords;
// 9 loads/thread vs 33 — issue-latency fix, K1 is the largest
// kernel at ~10-12us vs a 7.5us BW floor).
// img_s inner dim padded 96->100 (R2): Δoh LDS stride 300 ≡ 12
// mod 32 banks (was 288 ≡ 0 → ~6-way conflict).
// blocks [0,1024): conv; blocks [1024,1824): one 32x32 ft_w
// transpose+split tile per block.
// ============================================================
__global__ __launch_bounds__(256) void k1_fused(
    const float* __restrict__ images,   // (1024,3,96,96)
    const float* __restrict__ conv_w,   // (8,3,3,3)
    const float* __restrict__ ft_w,     // (800,1024)
    u16* __restrict__ vh, u16* __restrict__ vl,     // (1024,800)
    u16* __restrict__ bth, u16* __restrict__ btl)   // (1024,800) n-major
{
    __shared__ float img_s[3][29][100];   // padded (row stride 400B, 16B-aligned)
    __shared__ float w[216];
    __shared__ float tile[32][33];

    int t = threadIdx.x;

    if (blockIdx.x >= 1024) {
        int bid = blockIdx.x - 1024;       // 0..799
        int kb = bid / 32, nb = bid - kb * 32;
        int k0 = kb * 32, n0 = nb * 32;
        int tx = t & 31, ty = t >> 5;      // ty 0..7
        #pragma unroll
        for (int i = 0; i < 4; i++) {
            int k = ty + i * 8;
            tile[k][tx] = ft_w[(k0 + k) * 1024 + n0 + tx];
        }
        __syncthreads();
        #pragma unroll
        for (int i = 0; i < 4; i++) {
            int n = ty + i * 8;
            float wv = tile[tx][n];
            u16 hi = f2bf(wv);
            float lo = wv - bf2f(hi);
            bth[(n0 + n) * 800 + k0 + tx] = hi;
            btl[(n0 + n) * 800 + k0 + tx] = f2bf(lo);
        }
        return;
    }

    int b = blockIdx.x;
    if (t < 216) w[t] = conv_w[t];

    // float4 image staging: 3*29*24 = 2088 vec4 elements
    for (int i = t; i < 3 * 29 * 24; i += 256) {
        int ch  = i / (29 * 24);
        int rem = i - ch * (29 * 24);
        int lr  = rem / 24;
        int x4  = rem - lr * 24;
        int ih  = 10 * ((lr + 1) / 3) + (lr + 1) % 3 - 1;
        *(float4*)&img_s[ch][lr][x4 * 4] =
            *(const float4*)&images[((b * 3 + ch) * 96 + ih) * 96 + x4 * 4];
    }
    __syncthreads();

    for (int ridx = t; ridx < 800; ridx += 256) {
        int o  = ridx / 100;
        int p  = ridx - o * 100;
        int oh = p / 10;
        int ow = p - oh * 10;

        float sum = 0.0f;
        #pragma unroll
        for (int ic = 0; ic < 3; ic++) {
            const float* wc = &w[o * 27 + ic * 9];
            #pragma unroll
            for (int kh = 0; kh < 3; kh++) {
                int lr = 3 * oh + kh - 1;
                if (lr < 0) continue;
                #pragma unroll
                for (int kw = 0; kw < 3; kw++) {
                    int iw = ow * 10 + kw - 1;
                    if (iw < 0) continue;
                    sum = fmaf(img_s[ic][lr][iw], wc[kh * 3 + kw], sum);
                }
            }
        }
        float xc = fminf(fmaxf(sum, -1.0f), 1.0f);
        float binary = 1.0f / (1.0f + __expf(-10.0f * xc));
        float v = (binary > 0.5f) ? binary : 0.0f;
        u16 hi = f2bf(v);
        vh[b * 800 + ridx] = hi;
        vl[b * 800 + ridx] = f2bf(v - bf2f(hi));
    }
}

// ============================================================
// K2: split-bf16 MFMA GEMM, 64x64 tile, 4 waves, 2x2 frags,
// register-prefetch pipelining, split-K x2 via blockIdx.z
// (k in [0,416) / [416,800)) -> 512 blocks = 2 blocks/CU.
// Partials written RAW to two f32 buffers; K3 reduces.
// [R2-validated]
// ============================================================
__global__ __launch_bounds__(256) void k2_mfma(
    const u16* __restrict__ Ah, const u16* __restrict__ Al,   // (1024,800)
    const u16* __restrict__ Bh, const u16* __restrict__ Bl,   // (1024,800) n-major
    float* __restrict__ C0, float* __restrict__ C1)           // (1024,1024) partials
{
    __shared__ u16 sAh[64 * 40], sAl[64 * 40], sBh[64 * 40], sBl[64 * 40];
    int t = threadIdx.x;
    int m0 = blockIdx.y * 64, n0 = blockIdx.x * 64;
    int kb = (blockIdx.z == 0) ? 0 : 416;
    int ke = (blockIdx.z == 0) ? 416 : 800;
    float* C = (blockIdx.z == 0) ? C0 : C1;

    int w = t >> 6, lane = t & 63;
    int quad = lane >> 4, lo4 = lane & 15;
    int wm = (w >> 1) * 32, wn = (w & 1) * 32;

    int sr = t >> 2;   // staging row 0..63
    int sq = t & 3;    // 8-elem chunk 0..3
    const u16* gAh = Ah + (m0 + sr) * 800 + sq * 8;
    const u16* gAl = Al + (m0 + sr) * 800 + sq * 8;
    const u16* gBh = Bh + (n0 + sr) * 800 + sq * 8;
    const u16* gBl = Bl + (n0 + sr) * 800 + sq * 8;
    int sdst = sr * 40 + sq * 8;

    f32x4 acc[2][2] = {};

    uint4 rAh = *(const uint4*)(gAh + kb);
    uint4 rAl = *(const uint4*)(gAl + kb);
    uint4 rBh = *(const uint4*)(gBh + kb);
    uint4 rBl = *(const uint4*)(gBl + kb);

    for (int k0 = kb; k0 < ke; k0 += 32) {
        *(uint4*)&sAh[sdst] = rAh;
        *(uint4*)&sAl[sdst] = rAl;
        *(uint4*)&sBh[sdst] = rBh;
        *(uint4*)&sBl[sdst] = rBl;
        __syncthreads();

        if (k0 + 32 < ke) {                // prefetch next tile
            rAh = *(const uint4*)(gAh + k0 + 32);
            rAl = *(const uint4*)(gAl + k0 + 32);
            rBh = *(const uint4*)(gBh + k0 + 32);
            rBl = *(const uint4*)(gBl + k0 + 32);
        }

        short8 a_h[2], a_l[2], b_h[2], b_l[2];
        #pragma unroll
        for (int f = 0; f < 2; f++) {
            int mi = (wm + f * 16 + lo4) * 40 + quad * 8;
            a_h[f] = *(const short8*)&sAh[mi];
            a_l[f] = *(const short8*)&sAl[mi];
            int ni = (wn + f * 16 + lo4) * 40 + quad * 8;
            b_h[f] = *(const short8*)&sBh[ni];
            b_l[f] = *(const short8*)&sBl[ni];
        }
        #pragma unroll
        for (int fm = 0; fm < 2; fm++)
            #pragma unroll
            for (int fn = 0; fn < 2; fn++) {
                acc[fm][fn] = __builtin_amdgcn_mfma_f32_16x16x32_bf16(a_h[fm], b_h[fn], acc[fm][fn], 0, 0, 0);
                acc[fm][fn] = __builtin_amdgcn_mfma_f32_16x16x32_bf16(a_h[fm], b_l[fn], acc[fm][fn], 0, 0, 0);
                acc[fm][fn] = __builtin_amdgcn_mfma_f32_16x16x32_bf16(a_l[fm], b_h[fn], acc[fm][fn], 0, 0, 0);
            }
        __syncthreads();
    }

    // C/D layout: col = lane&15, row = quad*4 + reg.  Raw partial store.
    #pragma unroll
    for (int fm = 0; fm < 2; fm++) {
        #pragma unroll
        for (int fn = 0; fn < 2; fn++) {
            int n = n0 + wn + fn * 16 + lo4;
            #pragma unroll
            for (int r = 0; r < 4; r++) {
                int m = m0 + wm + fm * 16 + quad * 4 + r;
                C[m * 1024 + n] = acc[fm][fn][r];
            }
        }
    }
}

// ============================================================
// K3: per-row tail.  THIS ROUND: 2 waves per row (pair-space
// chunks 0..63 / 64..127), LDS combine of the 15 partials, finish
// on the half==0 wave.  Halves the serial load chain; grid 512
// blocks = 2 blocks/CU (was 1).  Reduces the two split-K partials
// + ft_b + clip inline.
// ============================================================
__global__ __launch_bounds__(256) void k3_tail(
    const float* __restrict__ l0a, // (1024,1024) partial 0
    const float* __restrict__ l0b, // (1024,1024) partial 1
    const float* __restrict__ ft_b,// (1024,)
    const float* __restrict__ w1,  // (15,1024)
    const float* __restrict__ b1,
    const float* __restrict__ w2,  // (32,15)
    const float* __restrict__ b2,
    const float* __restrict__ w3,  // (1,32)
    const float* __restrict__ b3,
    float* __restrict__ out)       // (1024,)
{
    __shared__ float red[2][15];   // [row][j], written by half==1 wave

    int wave = threadIdx.x >> 6;   // 0..3
    int lane = threadIdx.x & 63;
    int row  = wave >> 1;          // 0..1
    int half = wave & 1;           // 0..1
    int b = blockIdx.x * 2 + row;
    const float* pa = l0a + b * 1024;
    const float* pb = l0b + b * 1024;
    const float cc = 0.9921875f;   // 127/128

    float acc[15];
    #pragma unroll
    for (int j = 0; j < 15; j++) acc[j] = 0.f;

    {
        int k4 = (lane + half * 64) * 4;         // this wave's 64 chunks
        float4 a0 = *(const float4*)(pa + k4);
        float4 q0 = *(const float4*)(pb + k4);
        float4 f0 = *(const float4*)(ft_b + k4);
        float4 a1 = *(const float4*)(pa + k4 + 512);
        float4 q1 = *(const float4*)(pb + k4 + 512);
        float4 f1 = *(const float4*)(ft_b + k4 + 512);
        float4 x0, x1;
        x0.x = fminf(fmaxf(a0.x + q0.x + f0.x, 0.f), 1.f);
        x0.y = fminf(fmaxf(a0.y + q0.y + f0.y, 0.f), 1.f);
        x0.z = fminf(fmaxf(a0.z + q0.z + f0.z, 0.f), 1.f);
        x0.w = fminf(fmaxf(a0.w + q0.w + f0.w, 0.f), 1.f);
        x1.x = fminf(fmaxf(a1.x + q1.x + f1.x, 0.f), 1.f);
        x1.y = fminf(fmaxf(a1.y + q1.y + f1.y, 0.f), 1.f);
        x1.z = fminf(fmaxf(a1.z + q1.z + f1.z, 0.f), 1.f);
        x1.w = fminf(fmaxf(a1.w + q1.w + f1.w, 0.f), 1.f);

        float4 va, vb;
        va.x = x0.x * x1.x * cc; va.y = x0.y * x1.y * cc;
        va.z = x0.z * x1.z * cc; va.w = x0.w * x1.w * cc;
        vb.x = x0.x * cc; vb.y = x0.y * cc;
        vb.z = x0.z * cc; vb.w = x0.w * cc;
        #pragma unroll
        for (int j = 0; j < 15; j++) {
            float4 wa = *(const float4*)(w1 + j * 1024 + k4);
            float4 wb = *(const float4*)(w1 + j * 1024 + k4 + 512);
            acc[j] = fmaf(va.x, wa.x, acc[j]); acc[j] = fmaf(va.y, wa.y, acc[j]);
            acc[j] = fmaf(va.z, wa.z, acc[j]); acc[j] = fmaf(va.w, wa.w, acc[j]);
            acc[j] = fmaf(vb.x, wb.x, acc[j]); acc[j] = fmaf(vb.y, wb.y, acc[j]);
            acc[j] = fmaf(vb.z, wb.z, acc[j]); acc[j] = fmaf(vb.w, wb.w, acc[j]);
        }
    }

    #pragma unroll
    for (int j = 0; j < 15; j++) {
        #pragma unroll
        for (int m = 32; m >= 1; m >>= 1)
            acc[j] += __shfl_xor(acc[j], m, 64);
    }

    if (half == 1 && lane == 0) {
        #pragma unroll
        for (int j = 0; j < 15; j++) red[row][j] = acc[j];
    }
    __syncthreads();

    if (half == 0) {
        float h1[15];
        #pragma unroll
        for (int j = 0; j < 15; j++)
            h1[j] = fmaxf(acc[j] + red[row][j] + b1[j], 0.f);

        float contrib = 0.f;
        if (lane < 32) {
            float h2 = b2[lane];
            #pragma unroll
            for (int j = 0; j < 15; j++) h2 = fmaf(h1[j], w2[lane * 15 + j], h2);
            h2 = fmaxf(h2, 0.f);
            contrib = h2 * w3[lane];
        }
        #pragma unroll
        for (int m = 32; m >= 1; m >>= 1) contrib += __shfl_xor(contrib, m, 64);

        if (lane == 0) out[b] = contrib + b3[0];
    }
}

// ============================================================
extern "C" void kernel_launch(void* const* d_in, const int* in_sizes, int n_in,
                              void* d_out, int out_size, void* d_ws, size_t ws_size,
                              hipStream_t stream) {
    const float* images = (const float*)d_in[0];
    const float* conv_w = (const float*)d_in[1];
    const float* ft_w   = (const float*)d_in[2];
    const float* ft_b   = (const float*)d_in[3];
    const float* w1     = (const float*)d_in[4];
    const float* b1     = (const float*)d_in[5];
    const float* w2     = (const float*)d_in[6];
    const float* b2     = (const float*)d_in[7];
    const float* w3     = (const float*)d_in[8];
    const float* b3     = (const float*)d_in[9];
    float* out = (float*)d_out;

    const int NV = 1024 * 800;                 // 819200
    u16* vh  = (u16*)d_ws;
    u16* vl  = vh + NV;
    u16* bth = vl + NV;
    u16* btl = bth + NV;
    float* l0a = (float*)(btl + NV);           // (1024,1024) f32 partial 0
    float* l0b = l0a + 1024 * 1024;            // (1024,1024) f32 partial 1

    k1_fused<<<1824, 256, 0, stream>>>(images, conv_w, ft_w, vh, vl, bth, btl);
    k2_mfma<<<dim3(16, 16, 2), 256, 0, stream>>>(vh, vl, bth, btl, l0a, l0b);
    k3_tail<<<512, 256, 0, stream>>>(l0a, l0b, ft_b, w1, b1, w2, b2, w3, b3, out);
}